// Round 3
// baseline (2313.760 us; speedup 1.0000x reference)
//
#include <hip/hip_runtime.h>
#include <hip/hip_bf16.h>
#include <cstdint>
#include <cstddef>

// Problem constants
#define L_SEQ 2048
#define NBATCH 2
#define M_TOT 4096      // NBATCH * L_SEQ
#define DM 1536         // D_MODEL
#define DI 3072         // D_INNER
#define DS 96           // D_STATE
#define DTR 96          // DT_RANK
#define XDBL_LD 384     // padded 288 -> 384 (3 x 128 N-tiles)

typedef __attribute__((ext_vector_type(8))) short bf16x8;
typedef __attribute__((ext_vector_type(4))) float f32x4;
typedef __hip_bfloat16 bf16;

__device__ __forceinline__ float bf2f(bf16 h) { return __bfloat162float(h); }
__device__ __forceinline__ bf16 f2bf(float f) { return __float2bfloat16(f); }

__device__ __forceinline__ void gload_lds16(const void* g, void* lds) {
  __builtin_amdgcn_global_load_lds(
      (const __attribute__((address_space(1))) void*)g,
      (__attribute__((address_space(3))) void*)lds, 16, 0, 0);
}

// ---------------- K0: cond = t_cond @ cond_w + cond_b; gate pre-sigmoided ----
__global__ void cond_kernel(const float* __restrict__ t_cond,
                            const float* __restrict__ cond_w,
                            const float* __restrict__ cond_b,
                            float* __restrict__ cond_mod) {
  int idx = blockIdx.x * 256 + threadIdx.x;  // 0..9215
  int b = idx / 4608;
  int j = idx - b * 4608;
  const float* tc = t_cond + b * DM;
  float a0 = 0.f, a1 = 0.f, a2 = 0.f, a3 = 0.f;
#pragma unroll 4
  for (int k = 0; k < DM; k += 4) {
    a0 += tc[k + 0] * cond_w[(size_t)(k + 0) * 4608 + j];
    a1 += tc[k + 1] * cond_w[(size_t)(k + 1) * 4608 + j];
    a2 += tc[k + 2] * cond_w[(size_t)(k + 2) * 4608 + j];
    a3 += tc[k + 3] * cond_w[(size_t)(k + 3) * 4608 + j];
  }
  float acc = cond_b[j] + ((a0 + a1) + (a2 + a3));
  if (j >= 2 * DM) acc = 1.f / (1.f + __expf(-acc));  // sigmoid(gate)
  cond_mod[idx] = acc;
}

// ---------------- K1: RMSNorm + modulation -> xm (bf16) ----------------------
__global__ __launch_bounds__(256)
void rmsmod_kernel(const float* __restrict__ x,
                   const float* __restrict__ cond_mod,
                   bf16* __restrict__ xm) {
  int row = blockIdx.x;            // 0..4095
  int b = row >> 11;               // row / 2048
  const float* xr = x + (size_t)row * DM;
  const float* cm = cond_mod + b * 4608;
  float v[6];
  float ss = 0.f;
#pragma unroll
  for (int i = 0; i < 6; ++i) {
    v[i] = xr[threadIdx.x + i * 256];
    ss += v[i] * v[i];
  }
#pragma unroll
  for (int m = 32; m >= 1; m >>= 1) ss += __shfl_xor(ss, m);
  __shared__ float red[4];
  if ((threadIdx.x & 63) == 0) red[threadIdx.x >> 6] = ss;
  __syncthreads();
  float tot = red[0] + red[1] + red[2] + red[3];
  float rms = rsqrtf(tot * (1.f / (float)DM) + 1e-6f);
#pragma unroll
  for (int i = 0; i < 6; ++i) {
    int c = threadIdx.x + i * 256;
    float val = cm[3072 + c] * (v[i] * rms * (1.f + cm[c]) + cm[1536 + c]);
    xm[(size_t)row * DM + c] = f2bf(val);
  }
}

// ---------------- transpose + cast: src f32 (K,N) -> dst bf16 (Ndst,K) -------
// Rows N..Ndst-1 of dst are zero-filled (pad for N-tiling).
__global__ __launch_bounds__(256)
void transpose_cast(const float* __restrict__ src, bf16* __restrict__ dst,
                    int K, int N, int Ndst) {
  __shared__ float tile[64][65];
  int n0 = blockIdx.x * 64, k0 = blockIdx.y * 64;
#pragma unroll
  for (int i = 0; i < 16; ++i) {
    int idx = threadIdx.x + i * 256;
    int kk = idx >> 6, nn = idx & 63;
    float v = 0.f;
    if (k0 + kk < K && n0 + nn < N) v = src[(size_t)(k0 + kk) * N + (n0 + nn)];
    tile[kk][nn] = v;
  }
  __syncthreads();
#pragma unroll
  for (int i = 0; i < 16; ++i) {
    int idx = threadIdx.x + i * 256;
    int nn = idx >> 6, kk = idx & 63;
    if (n0 + nn < Ndst && k0 + kk < K)
      dst[(size_t)(n0 + nn) * K + (k0 + kk)] = f2bf(tile[kk][nn]);
  }
}

// ---------------- conv: depthwise causal conv(4) + bias + SiLU ---------------
__global__ __launch_bounds__(256)
void conv_kernel(const bf16* __restrict__ xz, const float* __restrict__ conv_w,
                 const float* __restrict__ conv_b, bf16* __restrict__ xconv) {
  int idx = blockIdx.x * 256 + threadIdx.x;  // 0 .. M_TOT*DI-1
  int d = idx % DI;
  int row = idx / DI;
  int l = row & (L_SEQ - 1);
  float4 w4 = *(const float4*)(conv_w + d * 4);
  const float wv[4] = {w4.x, w4.y, w4.z, w4.w};
  float acc = conv_b[d];
#pragma unroll
  for (int t = 0; t < 4; ++t) {
    int ll = l - 3 + t;
    if (ll >= 0) acc += bf2f(xz[(size_t)(row - 3 + t) * 6144 + d]) * wv[t];
  }
  xconv[idx] = f2bf(acc / (1.f + __expf(-acc)));  // silu
}

// ---------------- cast dt_raw slice of x_dbl to bf16 -------------------------
__global__ __launch_bounds__(256)
void dtraw_cast(const float* __restrict__ xdbl, bf16* __restrict__ dtraw) {
  int idx = blockIdx.x * 256 + threadIdx.x;  // 0 .. M_TOT*96-1
  int r = idx / DTR, c = idx - r * DTR;
  dtraw[idx] = f2bf(xdbl[(size_t)r * XDBL_LD + c]);
}

// ---------------- 128x128 bf16 MFMA GEMM (m97 structure) ---------------------
// A: (M, K) bf16 row-major lda; Bt: (N, K) bf16 row-major ldb.
// EPI: 0 = store bf16; 1 = store f32; 2 = softplus(acc + extra[c]) -> bf16;
//      3 = acc + extra[r*ldc+c] -> f32
template <int EPI>
__global__ __launch_bounds__(256)
void gemm128(const bf16* __restrict__ A, int lda, const bf16* __restrict__ Bt,
             int ldb, void* __restrict__ C, int ldc,
             const float* __restrict__ extra, int nTilesN, int K) {
  __shared__ __align__(16) bf16 As[128 * 32];
  __shared__ __align__(16) bf16 Bs[128 * 32];
  const int tid = threadIdx.x;
  const int lane = tid & 63;
  const int wid = tid >> 6;
  const int bm = (blockIdx.x / nTilesN) * 128;
  const int bn = (blockIdx.x % nTilesN) * 128;
  const int wr = wid >> 1, wc = wid & 1;
  f32x4 acc[4][4] = {};
  for (int k0 = 0; k0 < K; k0 += 32) {
#pragma unroll
    for (int it = 0; it < 2; ++it) {
      int chunk = (wid * 2 + it) * 64 + lane;  // 0..511
      int row = chunk >> 2;
      int ke = (chunk & 3) * 8;
      gload_lds16(A + (size_t)(bm + row) * lda + (k0 + ke),
                  (char*)As + (size_t)(wid * 2 + it) * 1024);
      gload_lds16(Bt + (size_t)(bn + row) * ldb + (k0 + ke),
                  (char*)Bs + (size_t)(wid * 2 + it) * 1024);
    }
    __syncthreads();
    bf16x8 af[4], bfr[4];
#pragma unroll
    for (int m = 0; m < 4; ++m)
      af[m] = *(const bf16x8*)(As + (wr * 64 + m * 16 + (lane & 15)) * 32 +
                               (lane >> 4) * 8);
#pragma unroll
    for (int n = 0; n < 4; ++n)
      bfr[n] = *(const bf16x8*)(Bs + (wc * 64 + n * 16 + (lane & 15)) * 32 +
                                (lane >> 4) * 8);
#pragma unroll
    for (int m = 0; m < 4; ++m)
#pragma unroll
      for (int n = 0; n < 4; ++n)
        acc[m][n] =
            __builtin_amdgcn_mfma_f32_16x16x32_bf16(af[m], bfr[n], acc[m][n], 0, 0, 0);
    __syncthreads();
  }
  const int r0 = bm + wr * 64 + (lane >> 4) * 4;
  const int c0 = bn + wc * 64 + (lane & 15);
#pragma unroll
  for (int m = 0; m < 4; ++m) {
#pragma unroll
    for (int n = 0; n < 4; ++n) {
      int c = c0 + n * 16;
#pragma unroll
      for (int j = 0; j < 4; ++j) {
        int r = r0 + m * 16 + j;
        size_t off = (size_t)r * ldc + c;
        float v = acc[m][n][j];
        if constexpr (EPI == 0) {
          ((bf16*)C)[off] = f2bf(v);
        } else if constexpr (EPI == 1) {
          ((float*)C)[off] = v;
        } else if constexpr (EPI == 2) {
          float t = v + extra[c];
          ((bf16*)C)[off] = f2bf(t > 20.f ? t : log1pf(__expf(t)));
        } else {
          ((float*)C)[off] = v + extra[off];
        }
      }
    }
  }
}

// ---------------- selective scan ---------------------------------------------
// 32 lanes per channel d, 3 states per lane. 8 channels per 256-thr block.
__global__ __launch_bounds__(256)
void scan_kernel(const bf16* __restrict__ dt, const bf16* __restrict__ xconv,
                 const bf16* __restrict__ xz, const float* __restrict__ xdbl,
                 const float* __restrict__ A_log, const float* __restrict__ Dp,
                 bf16* __restrict__ yy) {
  int blk = blockIdx.x;  // 0..767
  int b = blk / 384;
  int d = (blk % 384) * 8 + (threadIdx.x >> 5);
  int g = threadIdx.x & 31;
  int n0 = g * 3;
  float a0 = -__expf(A_log[(size_t)d * DS + n0 + 0]);
  float a1 = -__expf(A_log[(size_t)d * DS + n0 + 1]);
  float a2 = -__expf(A_log[(size_t)d * DS + n0 + 2]);
  float Dd = Dp[d];
  float s0 = 0.f, s1 = 0.f, s2 = 0.f;
  size_t base = (size_t)b * L_SEQ;
  for (int l = 0; l < L_SEQ; ++l) {
    size_t row = base + l;
    float dtv = bf2f(dt[row * DI + d]);
    float xv = bf2f(xconv[row * DI + d]);
    const float* bc = xdbl + row * XDBL_LD;
    float B0 = bc[96 + n0], B1 = bc[96 + n0 + 1], B2 = bc[96 + n0 + 2];
    float C0 = bc[192 + n0], C1 = bc[192 + n0 + 1], C2 = bc[192 + n0 + 2];
    float du = dtv * xv;
    s0 = s0 * __expf(dtv * a0) + du * B0;
    s1 = s1 * __expf(dtv * a1) + du * B1;
    s2 = s2 * __expf(dtv * a2) + du * B2;
    float p = s0 * C0 + s1 * C1 + s2 * C2;
    p += __shfl_xor(p, 16);
    p += __shfl_xor(p, 8);
    p += __shfl_xor(p, 4);
    p += __shfl_xor(p, 2);
    p += __shfl_xor(p, 1);
    if (g == 0) {
      float zv = bf2f(xz[row * 6144 + DI + d]);
      float y = p + xv * Dd;
      float o = y * (zv / (1.f + __expf(-zv)));
      yy[row * DI + d] = f2bf(o);
    }
  }
}

// ---------------- launch ------------------------------------------------------
extern "C" void kernel_launch(void* const* d_in, const int* in_sizes, int n_in,
                              void* d_out, int out_size, void* d_ws,
                              size_t ws_size, hipStream_t stream) {
  const float* x = (const float*)d_in[0];
  const float* t_cond = (const float*)d_in[1];
  const float* cond_w = (const float*)d_in[2];
  const float* cond_b = (const float*)d_in[3];
  const float* in_w = (const float*)d_in[4];
  const float* conv_w = (const float*)d_in[5];
  const float* conv_b = (const float*)d_in[6];
  const float* xproj_w = (const float*)d_in[7];
  const float* dt_w = (const float*)d_in[8];
  const float* dt_b = (const float*)d_in[9];
  const float* A_log = (const float*)d_in[10];
  const float* D_p = (const float*)d_in[11];
  const float* out_w = (const float*)d_in[12];
  float* out = (float*)d_out;

  char* ws = (char*)d_ws;
  size_t off = 0;
  auto alloc = [&](size_t bytes) {
    void* p = ws + off;
    off += (bytes + 255) & ~(size_t)255;
    return p;
  };
  // total ~152 MB
  float* cond_mod = (float*)alloc(2 * 4608 * 4);
  // region A: xm (12.58MB) + in_w_t (18.87MB); both dead after G1 -> reuse for dt
  char* regionA = (char*)alloc(31457280);
  bf16* xm = (bf16*)regionA;
  bf16* in_w_t = (bf16*)(regionA + (size_t)M_TOT * DM * 2);
  bf16* dtbuf = (bf16*)regionA;  // (M_TOT, DI) bf16, written by G3 after G1
  bf16* xproj_t = (bf16*)alloc((size_t)XDBL_LD * DI * 2);
  bf16* dtw_t = (bf16*)alloc((size_t)DI * DTR * 2);
  bf16* outw_t = (bf16*)alloc((size_t)DM * DI * 2);
  bf16* xz = (bf16*)alloc((size_t)M_TOT * 6144 * 2);
  bf16* xconv = (bf16*)alloc((size_t)M_TOT * DI * 2);
  float* xdbl = (float*)alloc((size_t)M_TOT * XDBL_LD * 4);
  bf16* dtraw = (bf16*)alloc((size_t)M_TOT * DTR * 2);
  bf16* yy = (bf16*)alloc((size_t)M_TOT * DI * 2);

  // 1. conditioning
  cond_kernel<<<36, 256, 0, stream>>>(t_cond, cond_w, cond_b, cond_mod);
  // 2. rmsnorm + modulation
  rmsmod_kernel<<<M_TOT, 256, 0, stream>>>(x, cond_mod, xm);
  // 3. weight transpose-casts
  transpose_cast<<<dim3(96, 24), 256, 0, stream>>>(in_w, in_w_t, 1536, 6144, 6144);
  transpose_cast<<<dim3(6, 48), 256, 0, stream>>>(xproj_w, xproj_t, 3072, 288, 384);
  transpose_cast<<<dim3(48, 2), 256, 0, stream>>>(dt_w, dtw_t, 96, 3072, 3072);
  transpose_cast<<<dim3(24, 48), 256, 0, stream>>>(out_w, outw_t, 3072, 1536, 1536);
  // 4. G1: xz = xm @ in_w  (4096 x 6144 x 1536) -> bf16
  gemm128<0><<<32 * 48, 256, 0, stream>>>(xm, DM, in_w_t, DM, xz, 6144,
                                          nullptr, 48, DM);
  // 5. conv + silu
  conv_kernel<<<(M_TOT * DI) / 256, 256, 0, stream>>>(xz, conv_w, conv_b, xconv);
  // 6. G2: x_dbl = xconv @ xproj (4096 x 384pad x 3072) -> f32
  gemm128<1><<<32 * 3, 256, 0, stream>>>(xconv, DI, xproj_t, DI, xdbl, XDBL_LD,
                                         nullptr, 3, DI);
  // 7. dt_raw cast
  dtraw_cast<<<(M_TOT * DTR) / 256, 256, 0, stream>>>(xdbl, dtraw);
  // 8. G3: dt = softplus(dt_raw @ dt_w + dt_b) (4096 x 3072 x 96) -> bf16
  gemm128<2><<<32 * 24, 256, 0, stream>>>(dtraw, DTR, dtw_t, DTR, dtbuf, DI,
                                          dt_b, 24, DTR);
  // 9. selective scan + gated epilogue -> yy (bf16)
  scan_kernel<<<768, 256, 0, stream>>>(dtbuf, xconv, xz, xdbl, A_log, D_p, yy);
  // 10. G4: out = x + yy @ out_w (4096 x 1536 x 3072) -> f32
  gemm128<3><<<32 * 12, 256, 0, stream>>>(yy, DI, outw_t, DI, out, DM, x, 12,
                                          DI);
}

// Round 5
// 1485.690 us; speedup vs baseline: 1.5574x; 1.5574x over previous
//
#include <hip/hip_runtime.h>
#include <hip/hip_bf16.h>
#include <cstdint>
#include <cstddef>

// Problem constants
#define L_SEQ 2048
#define NBATCH 2
#define M_TOT 4096      // NBATCH * L_SEQ
#define DM 1536         // D_MODEL
#define DI 3072         // D_INNER
#define DS 96           // D_STATE
#define DTR 96          // DT_RANK
#define XDBL_LD 384     // padded 288 -> 384 (3 x 128 N-tiles)

typedef __attribute__((ext_vector_type(8))) short bf16x8;
typedef __attribute__((ext_vector_type(4))) float f32x4;
typedef __hip_bfloat16 bf16;

__device__ __forceinline__ float bf2f(bf16 h) { return __bfloat162float(h); }
__device__ __forceinline__ bf16 f2bf(float f) { return __float2bfloat16(f); }

__device__ __forceinline__ void gload_lds16(const void* g, void* lds) {
  __builtin_amdgcn_global_load_lds(
      (const __attribute__((address_space(1))) void*)g,
      (__attribute__((address_space(3))) void*)lds, 16, 0, 0);
}

// ---------------- K0: cond = t_cond @ cond_w + cond_b; gate pre-sigmoided ----
__global__ void cond_kernel(const float* __restrict__ t_cond,
                            const float* __restrict__ cond_w,
                            const float* __restrict__ cond_b,
                            float* __restrict__ cond_mod) {
  int idx = blockIdx.x * 256 + threadIdx.x;  // 0..9215
  int b = idx / 4608;
  int j = idx - b * 4608;
  const float* tc = t_cond + b * DM;
  float a0 = 0.f, a1 = 0.f, a2 = 0.f, a3 = 0.f;
#pragma unroll 4
  for (int k = 0; k < DM; k += 4) {
    a0 += tc[k + 0] * cond_w[(size_t)(k + 0) * 4608 + j];
    a1 += tc[k + 1] * cond_w[(size_t)(k + 1) * 4608 + j];
    a2 += tc[k + 2] * cond_w[(size_t)(k + 2) * 4608 + j];
    a3 += tc[k + 3] * cond_w[(size_t)(k + 3) * 4608 + j];
  }
  float acc = cond_b[j] + ((a0 + a1) + (a2 + a3));
  if (j >= 2 * DM) acc = 1.f / (1.f + __expf(-acc));  // sigmoid(gate)
  cond_mod[idx] = acc;
}

// ---------------- K1: RMSNorm + modulation -> xm (bf16) ----------------------
__global__ __launch_bounds__(256)
void rmsmod_kernel(const float* __restrict__ x,
                   const float* __restrict__ cond_mod,
                   bf16* __restrict__ xm) {
  int row = blockIdx.x;            // 0..4095
  int b = row >> 11;               // row / 2048
  const float* xr = x + (size_t)row * DM;
  const float* cm = cond_mod + b * 4608;
  float v[6];
  float ss = 0.f;
#pragma unroll
  for (int i = 0; i < 6; ++i) {
    v[i] = xr[threadIdx.x + i * 256];
    ss += v[i] * v[i];
  }
#pragma unroll
  for (int m = 32; m >= 1; m >>= 1) ss += __shfl_xor(ss, m);
  __shared__ float red[4];
  if ((threadIdx.x & 63) == 0) red[threadIdx.x >> 6] = ss;
  __syncthreads();
  float tot = red[0] + red[1] + red[2] + red[3];
  float rms = rsqrtf(tot * (1.f / (float)DM) + 1e-6f);
#pragma unroll
  for (int i = 0; i < 6; ++i) {
    int c = threadIdx.x + i * 256;
    float val = cm[3072 + c] * (v[i] * rms * (1.f + cm[c]) + cm[1536 + c]);
    xm[(size_t)row * DM + c] = f2bf(val);
  }
}

// ---------------- transpose + cast: src f32 (K,N) -> dst bf16 (Ndst,K) -------
// Rows N..Ndst-1 of dst are zero-filled (pad for N-tiling).
__global__ __launch_bounds__(256)
void transpose_cast(const float* __restrict__ src, bf16* __restrict__ dst,
                    int K, int N, int Ndst) {
  __shared__ float tile[64][65];
  int n0 = blockIdx.x * 64, k0 = blockIdx.y * 64;
#pragma unroll
  for (int i = 0; i < 16; ++i) {
    int idx = threadIdx.x + i * 256;
    int kk = idx >> 6, nn = idx & 63;
    float v = 0.f;
    if (k0 + kk < K && n0 + nn < N) v = src[(size_t)(k0 + kk) * N + (n0 + nn)];
    tile[kk][nn] = v;
  }
  __syncthreads();
#pragma unroll
  for (int i = 0; i < 16; ++i) {
    int idx = threadIdx.x + i * 256;
    int nn = idx >> 6, kk = idx & 63;
    if (n0 + nn < Ndst && k0 + kk < K)
      dst[(size_t)(n0 + nn) * K + (k0 + kk)] = f2bf(tile[kk][nn]);
  }
}

// ---------------- tbf16: bf16 [b*2048+l][srcLD] (col off+d) -> [b*3072+d][2048]
// Grid: 2 * 32 * 48 blocks (b, l-tile, d-tile), 256 threads.
__global__ __launch_bounds__(256)
void tbf16_kernel(const bf16* __restrict__ src, int srcLD, int colOff,
                  bf16* __restrict__ dst) {
  __shared__ unsigned short tile[64][72];  // 72: rows 144B (16B-aligned), low conflict
  int bz = blockIdx.x / (48 * 32);
  int rem = blockIdx.x % (48 * 32);
  int td = rem % 48, tl = rem / 48;
  int l0 = tl * 64, d0 = td * 64;
  const bf16* s0 = src + ((size_t)bz * L_SEQ + l0) * srcLD + colOff + d0;
  // load phase: 512 chunks of 8 bf16 (16B); thread t -> row t>>3, col8 t&7
#pragma unroll
  for (int it = 0; it < 2; ++it) {
    int t = threadIdx.x + it * 256;
    int r = t >> 3, c8 = t & 7;
    bf16x8 v = *(const bf16x8*)(s0 + (size_t)r * srcLD + c8 * 8);
    *(bf16x8*)&tile[r][c8 * 8] = v;
  }
  __syncthreads();
  // store phase: thread t -> d = t&63, l16 = t>>6 (16 l's per thread)
  int dd = threadIdx.x & 63;
  int l16 = threadIdx.x >> 6;
  bf16* dp = dst + ((size_t)bz * DI + d0 + dd) * L_SEQ + l0 + l16 * 16;
  bf16x8 v0, v1;
#pragma unroll
  for (int j = 0; j < 8; ++j) v0[j] = (short)tile[l16 * 16 + j][dd];
#pragma unroll
  for (int j = 0; j < 8; ++j) v1[j] = (short)tile[l16 * 16 + 8 + j][dd];
  *(bf16x8*)dp = v0;
  *(bf16x8*)(dp + 8) = v1;
}

// ---------------- conv: depthwise causal conv(4) + bias + SiLU ---------------
__global__ __launch_bounds__(256)
void conv_kernel(const bf16* __restrict__ xz, const float* __restrict__ conv_w,
                 const float* __restrict__ conv_b, bf16* __restrict__ xconv) {
  int idx = blockIdx.x * 256 + threadIdx.x;  // 0 .. M_TOT*DI-1
  int d = idx % DI;
  int row = idx / DI;
  int l = row & (L_SEQ - 1);
  float4 w4 = *(const float4*)(conv_w + d * 4);
  const float wv[4] = {w4.x, w4.y, w4.z, w4.w};
  float acc = conv_b[d];
#pragma unroll
  for (int t = 0; t < 4; ++t) {
    int ll = l - 3 + t;
    if (ll >= 0) acc += bf2f(xz[(size_t)(row - 3 + t) * 6144 + d]) * wv[t];
  }
  xconv[idx] = f2bf(acc / (1.f + __expf(-acc)));  // silu
}

// ---------------- cast dt_raw slice of x_dbl to bf16 -------------------------
__global__ __launch_bounds__(256)
void dtraw_cast(const float* __restrict__ xdbl, bf16* __restrict__ dtraw) {
  int idx = blockIdx.x * 256 + threadIdx.x;  // 0 .. M_TOT*96-1
  int r = idx / DTR, c = idx - r * DTR;
  dtraw[idx] = f2bf(xdbl[(size_t)r * XDBL_LD + c]);
}

// ---------------- 128x128 bf16 MFMA GEMM (m97 structure) ---------------------
// A: (M, K) bf16 row-major lda; Bt: (N, K) bf16 row-major ldb.
// EPI: 0 = store bf16; 1 = store f32; 2 = softplus(acc + extra[c]) -> bf16;
//      3 = acc + extra[r*ldc+c] -> f32
template <int EPI>
__global__ __launch_bounds__(256)
void gemm128(const bf16* __restrict__ A, int lda, const bf16* __restrict__ Bt,
             int ldb, void* __restrict__ C, int ldc,
             const float* __restrict__ extra, int nTilesN, int K) {
  __shared__ __align__(16) bf16 As[128 * 32];
  __shared__ __align__(16) bf16 Bs[128 * 32];
  const int tid = threadIdx.x;
  const int lane = tid & 63;
  const int wid = tid >> 6;
  const int bm = (blockIdx.x / nTilesN) * 128;
  const int bn = (blockIdx.x % nTilesN) * 128;
  const int wr = wid >> 1, wc = wid & 1;
  f32x4 acc[4][4] = {};
  for (int k0 = 0; k0 < K; k0 += 32) {
#pragma unroll
    for (int it = 0; it < 2; ++it) {
      int chunk = (wid * 2 + it) * 64 + lane;  // 0..511
      int row = chunk >> 2;
      int ke = (chunk & 3) * 8;
      gload_lds16(A + (size_t)(bm + row) * lda + (k0 + ke),
                  (char*)As + (size_t)(wid * 2 + it) * 1024);
      gload_lds16(Bt + (size_t)(bn + row) * ldb + (k0 + ke),
                  (char*)Bs + (size_t)(wid * 2 + it) * 1024);
    }
    __syncthreads();
    bf16x8 af[4], bfr[4];
#pragma unroll
    for (int m = 0; m < 4; ++m)
      af[m] = *(const bf16x8*)(As + (wr * 64 + m * 16 + (lane & 15)) * 32 +
                               (lane >> 4) * 8);
#pragma unroll
    for (int n = 0; n < 4; ++n)
      bfr[n] = *(const bf16x8*)(Bs + (wc * 64 + n * 16 + (lane & 15)) * 32 +
                                (lane >> 4) * 8);
#pragma unroll
    for (int m = 0; m < 4; ++m)
#pragma unroll
      for (int n = 0; n < 4; ++n)
        acc[m][n] =
            __builtin_amdgcn_mfma_f32_16x16x32_bf16(af[m], bfr[n], acc[m][n], 0, 0, 0);
    __syncthreads();
  }
  const int r0 = bm + wr * 64 + (lane >> 4) * 4;
  const int c0 = bn + wc * 64 + (lane & 15);
#pragma unroll
  for (int m = 0; m < 4; ++m) {
#pragma unroll
    for (int n = 0; n < 4; ++n) {
      int c = c0 + n * 16;
#pragma unroll
      for (int j = 0; j < 4; ++j) {
        int r = r0 + m * 16 + j;
        size_t off = (size_t)r * ldc + c;
        float v = acc[m][n][j];
        if constexpr (EPI == 0) {
          ((bf16*)C)[off] = f2bf(v);
        } else if constexpr (EPI == 1) {
          ((float*)C)[off] = v;
        } else if constexpr (EPI == 2) {
          float t = v + extra[c];
          ((bf16*)C)[off] = f2bf(t > 20.f ? t : log1pf(__expf(t)));
        } else {
          ((float*)C)[off] = v + extra[off];
        }
      }
    }
  }
}

// ---------------- selective scan v2 ------------------------------------------
// 16 lanes/channel, 6 states/lane. Block = 128 thr = 8 channels. Grid = 768.
// Streams dtT/xcT/zT are [ch][2048] bf16 (chunk-of-8 register prefetch).
// B/C from xdbl (f32, L2-hot) with depth-2 register rolling prefetch.
__global__ __launch_bounds__(128)
void scan2_kernel(const bf16* __restrict__ dtT, const bf16* __restrict__ xcT,
                  const bf16* __restrict__ zT, const float* __restrict__ xdbl,
                  const float* __restrict__ A_log, const float* __restrict__ Dp,
                  bf16* __restrict__ yy) {
  const int tid = threadIdx.x;
  const int g = tid & 15;        // lane within channel group
  const int cl = tid >> 4;       // 0..7 channel within block
  const int CH = blockIdx.x * 8 + cl;  // 0..6143
  const int b = CH >= DI ? 1 : 0;
  const int d = CH - b * DI;
  const int n0 = g * 6;

  float a[6];
#pragma unroll
  for (int j = 0; j < 6; ++j) a[j] = -__expf(A_log[(size_t)d * DS + n0 + j]);
  const float Dd = Dp[d];
  float s[6] = {0.f, 0.f, 0.f, 0.f, 0.f, 0.f};

  const bf16* dtp = dtT + (size_t)CH * L_SEQ;
  const bf16* xcp = xcT + (size_t)CH * L_SEQ;
  const bf16* zp = zT + (size_t)CH * L_SEQ;
  const float* xb = xdbl + (size_t)b * L_SEQ * XDBL_LD;
  bf16* yp = yy + (size_t)b * L_SEQ * DI + d;

  // BC rolling prefetch slots (parity-indexed; all indices literal post-unroll)
  float2 B2[2][3], C2[2][3];
#pragma unroll
  for (int sl = 0; sl < 2; ++sl) {
    const float2* pb = (const float2*)(xb + (size_t)sl * XDBL_LD + DTR + n0);
    const float2* pc = (const float2*)(xb + (size_t)sl * XDBL_LD + DTR + DS + n0);
#pragma unroll
    for (int j = 0; j < 3; ++j) {
      B2[sl][j] = pb[j];
      C2[sl][j] = pc[j];
    }
  }
  bf16x8 dt8 = *(const bf16x8*)dtp;
  bf16x8 xc8 = *(const bf16x8*)xcp;
  bf16x8 z8 = *(const bf16x8*)zp;

  for (int l0 = 0; l0 < L_SEQ; l0 += 8) {
    // prefetch next chunk's streams (wraps harmlessly on last chunk)
    int ln = (l0 + 8) & (L_SEQ - 1);
    bf16x8 dt8n = *(const bf16x8*)(dtp + ln);
    bf16x8 xc8n = *(const bf16x8*)(xcp + ln);
    bf16x8 z8n = *(const bf16x8*)(zp + ln);
#pragma unroll
    for (int i = 0; i < 8; ++i) {
      int l = l0 + i;
      float dtv = __uint_as_float(((unsigned)(unsigned short)dt8[i]) << 16);
      float xv = __uint_as_float(((unsigned)(unsigned short)xc8[i]) << 16);
      float du = dtv * xv;
      float pj = 0.f;
#pragma unroll
      for (int j = 0; j < 6; ++j) {
        float Bj = (j & 1) ? B2[i & 1][j >> 1].y : B2[i & 1][j >> 1].x;
        float Cj = (j & 1) ? C2[i & 1][j >> 1].y : C2[i & 1][j >> 1].x;
        s[j] = s[j] * __expf(dtv * a[j]) + du * Bj;
        pj += s[j] * Cj;
      }
      // refill slot (i&1) with step l+2
      int lp = l + 2;
      if (lp > L_SEQ - 1) lp = L_SEQ - 1;
      {
        const float2* pb = (const float2*)(xb + (size_t)lp * XDBL_LD + DTR + n0);
        const float2* pc =
            (const float2*)(xb + (size_t)lp * XDBL_LD + DTR + DS + n0);
#pragma unroll
        for (int j = 0; j < 3; ++j) {
          B2[i & 1][j] = pb[j];
          C2[i & 1][j] = pc[j];
        }
      }
      pj += __shfl_xor(pj, 8);
      pj += __shfl_xor(pj, 4);
      pj += __shfl_xor(pj, 2);
      pj += __shfl_xor(pj, 1);
      if (g == 0) {
        float zv = __uint_as_float(((unsigned)(unsigned short)z8[i]) << 16);
        float y = pj + xv * Dd;
        yp[(size_t)l * DI] = f2bf(y * (zv / (1.f + __expf(-zv))));
      }
    }
    dt8 = dt8n;
    xc8 = xc8n;
    z8 = z8n;
  }
}

// ---------------- launch ------------------------------------------------------
extern "C" void kernel_launch(void* const* d_in, const int* in_sizes, int n_in,
                              void* d_out, int out_size, void* d_ws,
                              size_t ws_size, hipStream_t stream) {
  const float* x = (const float*)d_in[0];
  const float* t_cond = (const float*)d_in[1];
  const float* cond_w = (const float*)d_in[2];
  const float* cond_b = (const float*)d_in[3];
  const float* in_w = (const float*)d_in[4];
  const float* conv_w = (const float*)d_in[5];
  const float* conv_b = (const float*)d_in[6];
  const float* xproj_w = (const float*)d_in[7];
  const float* dt_w = (const float*)d_in[8];
  const float* dt_b = (const float*)d_in[9];
  const float* A_log = (const float*)d_in[10];
  const float* D_p = (const float*)d_in[11];
  const float* out_w = (const float*)d_in[12];
  float* out = (float*)d_out;

  char* ws = (char*)d_ws;
  size_t off = 0;
  auto alloc = [&](size_t bytes) {
    void* p = ws + off;
    off += (bytes + 255) & ~(size_t)255;
    return p;
  };
  // ~150.9 MB total (within the 151.6 MB footprint proven in round 3)
  float* cond_mod = (float*)alloc(2 * 4608 * 4);
  // regionA: xm (12.58MB) + in_w_t (18.87MB), both dead after G1 -> xcT
  char* regionA = (char*)alloc(31457280);
  bf16* xm = (bf16*)regionA;
  bf16* in_w_t = (bf16*)(regionA + (size_t)M_TOT * DM * 2);
  bf16* xcT = (bf16*)regionA;  // [2*3072][2048] bf16, written step 10
  bf16* xproj_t = (bf16*)alloc((size_t)XDBL_LD * DI * 2);
  bf16* dtw_t = (bf16*)alloc((size_t)DI * DTR * 2);
  bf16* outw_t = (bf16*)alloc((size_t)DM * DI * 2);
  // xz region (50.33MB): dead after zT (step 11) -> dtT + dtraw + yy
  char* xzR = (char*)alloc((size_t)M_TOT * 6144 * 2);
  bf16* xz = (bf16*)xzR;
  bf16* dtT = (bf16*)xzR;                          // 25.17MB
  bf16* dtraw = (bf16*)(xzR + 25165824);           // 0.79MB
  bf16* yy = (bf16*)(xzR + 25952256);              // 12.58MB
  // xconv region (25.17MB): dead after xcT (step 10) -> zT (step 11)
  char* xcR = (char*)alloc((size_t)M_TOT * DI * 2);
  bf16* xconv = (bf16*)xcR;
  bf16* zT = (bf16*)xcR;
  float* xdbl = (float*)alloc((size_t)M_TOT * XDBL_LD * 4);
  bf16* dtbuf = (bf16*)alloc((size_t)M_TOT * DI * 2);

  // 1. conditioning
  cond_kernel<<<36, 256, 0, stream>>>(t_cond, cond_w, cond_b, cond_mod);
  // 2. rmsnorm + modulation
  rmsmod_kernel<<<M_TOT, 256, 0, stream>>>(x, cond_mod, xm);
  // 3-6. weight transpose-casts
  transpose_cast<<<dim3(96, 24), 256, 0, stream>>>(in_w, in_w_t, 1536, 6144, 6144);
  transpose_cast<<<dim3(6, 48), 256, 0, stream>>>(xproj_w, xproj_t, 3072, 288, 384);
  transpose_cast<<<dim3(48, 2), 256, 0, stream>>>(dt_w, dtw_t, 96, 3072, 3072);
  transpose_cast<<<dim3(24, 48), 256, 0, stream>>>(out_w, outw_t, 3072, 1536, 1536);
  // 7. G1: xz = xm @ in_w  (4096 x 6144 x 1536) -> bf16
  gemm128<0><<<32 * 48, 256, 0, stream>>>(xm, DM, in_w_t, DM, xz, 6144,
                                          nullptr, 48, DM);
  // 8. conv + silu
  conv_kernel<<<(M_TOT * DI) / 256, 256, 0, stream>>>(xz, conv_w, conv_b, xconv);
  // 9. G2: x_dbl = xconv @ xproj (4096 x 384pad x 3072) -> f32
  gemm128<1><<<32 * 3, 256, 0, stream>>>(xconv, DI, xproj_t, DI, xdbl, XDBL_LD,
                                         nullptr, 3, DI);
  // 10. xcT = transpose(xconv)   (frees xconv region)
  tbf16_kernel<<<2 * 48 * 32, 256, 0, stream>>>(xconv, DI, 0, xcT);
  // 11. zT = transpose(z half of xz)   (frees xz region)
  tbf16_kernel<<<2 * 48 * 32, 256, 0, stream>>>(xz, 6144, DI, zT);
  // 12. dt_raw cast (into freed xz region)
  dtraw_cast<<<(M_TOT * DTR) / 256, 256, 0, stream>>>(xdbl, dtraw);
  // 13. G3: dt = softplus(dt_raw @ dt_w + dt_b) (4096 x 3072 x 96) -> bf16
  gemm128<2><<<32 * 24, 256, 0, stream>>>(dtraw, DTR, dtw_t, DTR, dtbuf, DI,
                                          dt_b, 24, DTR);
  // 14. dtT = transpose(dt)
  tbf16_kernel<<<2 * 48 * 32, 256, 0, stream>>>(dtbuf, DI, 0, dtT);
  // 15. selective scan v2 + gated epilogue -> yy
  scan2_kernel<<<768, 128, 0, stream>>>(dtT, xcT, zT, xdbl, A_log, D_p, yy);
  // 16. G4: out = x + yy @ out_w (4096 x 1536 x 3072) -> f32
  gemm128<3><<<32 * 12, 256, 0, stream>>>(yy, DI, outw_t, DI, out, DM, x, 12,
                                          DI);
}

// Round 6
// 1231.001 us; speedup vs baseline: 1.8796x; 1.2069x over previous
//
#include <hip/hip_runtime.h>
#include <hip/hip_bf16.h>
#include <cstdint>
#include <cstddef>

// Problem constants
#define L_SEQ 2048
#define NBATCH 2
#define M_TOT 4096      // NBATCH * L_SEQ
#define DM 1536         // D_MODEL
#define DI 3072         // D_INNER
#define DS 96           // D_STATE
#define DTR 96          // DT_RANK
#define XDBL_LD 384     // padded 288 -> 384 (3 x 128 N-tiles)

#define NCHUNK 8
#define CLEN 256        // steps per chunk (L_SEQ / NCHUNK)
#define SUBS 16         // steps per LDS sub-chunk
#define NSUB (CLEN / SUBS)

typedef __attribute__((ext_vector_type(8))) short bf16x8;
typedef __attribute__((ext_vector_type(4))) float f32x4;
typedef __hip_bfloat16 bf16;

__device__ __forceinline__ float bf2f(bf16 h) { return __bfloat162float(h); }
__device__ __forceinline__ bf16 f2bf(float f) { return __float2bfloat16(f); }
__device__ __forceinline__ float bfbits(short h) {
  return __uint_as_float(((unsigned)(unsigned short)h) << 16);
}
#if __has_builtin(__builtin_amdgcn_exp2f)
__device__ __forceinline__ float fexp2(float x) { return __builtin_amdgcn_exp2f(x); }
#else
__device__ __forceinline__ float fexp2(float x) { return exp2f(x); }
#endif
#define LOG2E 1.44269504f

__device__ __forceinline__ void gload_lds16(const void* g, void* lds) {
  __builtin_amdgcn_global_load_lds(
      (const __attribute__((address_space(1))) void*)g,
      (__attribute__((address_space(3))) void*)lds, 16, 0, 0);
}

// ---------------- K0: cond = t_cond @ cond_w + cond_b; gate pre-sigmoided ----
__global__ void cond_kernel(const float* __restrict__ t_cond,
                            const float* __restrict__ cond_w,
                            const float* __restrict__ cond_b,
                            float* __restrict__ cond_mod) {
  int idx = blockIdx.x * 256 + threadIdx.x;  // 0..9215
  int b = idx / 4608;
  int j = idx - b * 4608;
  const float* tc = t_cond + b * DM;
  float a0 = 0.f, a1 = 0.f, a2 = 0.f, a3 = 0.f;
#pragma unroll 4
  for (int k = 0; k < DM; k += 4) {
    a0 += tc[k + 0] * cond_w[(size_t)(k + 0) * 4608 + j];
    a1 += tc[k + 1] * cond_w[(size_t)(k + 1) * 4608 + j];
    a2 += tc[k + 2] * cond_w[(size_t)(k + 2) * 4608 + j];
    a3 += tc[k + 3] * cond_w[(size_t)(k + 3) * 4608 + j];
  }
  float acc = cond_b[j] + ((a0 + a1) + (a2 + a3));
  if (j >= 2 * DM) acc = 1.f / (1.f + __expf(-acc));  // sigmoid(gate)
  cond_mod[idx] = acc;
}

// ---------------- K1: RMSNorm + modulation -> xm (bf16) ----------------------
__global__ __launch_bounds__(256)
void rmsmod_kernel(const float* __restrict__ x,
                   const float* __restrict__ cond_mod,
                   bf16* __restrict__ xm) {
  int row = blockIdx.x;            // 0..4095
  int b = row >> 11;               // row / 2048
  const float* xr = x + (size_t)row * DM;
  const float* cm = cond_mod + b * 4608;
  float v[6];
  float ss = 0.f;
#pragma unroll
  for (int i = 0; i < 6; ++i) {
    v[i] = xr[threadIdx.x + i * 256];
    ss += v[i] * v[i];
  }
#pragma unroll
  for (int m = 32; m >= 1; m >>= 1) ss += __shfl_xor(ss, m);
  __shared__ float red[4];
  if ((threadIdx.x & 63) == 0) red[threadIdx.x >> 6] = ss;
  __syncthreads();
  float tot = red[0] + red[1] + red[2] + red[3];
  float rms = rsqrtf(tot * (1.f / (float)DM) + 1e-6f);
#pragma unroll
  for (int i = 0; i < 6; ++i) {
    int c = threadIdx.x + i * 256;
    float val = cm[3072 + c] * (v[i] * rms * (1.f + cm[c]) + cm[1536 + c]);
    xm[(size_t)row * DM + c] = f2bf(val);
  }
}

// ---------------- transpose + cast: src f32 (K,N) -> dst bf16 (Ndst,K) -------
// Rows N..Ndst-1 of dst are zero-filled (pad for N-tiling).
__global__ __launch_bounds__(256)
void transpose_cast(const float* __restrict__ src, bf16* __restrict__ dst,
                    int K, int N, int Ndst) {
  __shared__ float tile[64][65];
  int n0 = blockIdx.x * 64, k0 = blockIdx.y * 64;
#pragma unroll
  for (int i = 0; i < 16; ++i) {
    int idx = threadIdx.x + i * 256;
    int kk = idx >> 6, nn = idx & 63;
    float v = 0.f;
    if (k0 + kk < K && n0 + nn < N) v = src[(size_t)(k0 + kk) * N + (n0 + nn)];
    tile[kk][nn] = v;
  }
  __syncthreads();
#pragma unroll
  for (int i = 0; i < 16; ++i) {
    int idx = threadIdx.x + i * 256;
    int nn = idx >> 6, kk = idx & 63;
    if (n0 + nn < Ndst && k0 + kk < K)
      dst[(size_t)(n0 + nn) * K + (k0 + kk)] = f2bf(tile[kk][nn]);
  }
}

// ---------------- tbf16: bf16 [b*2048+l][srcLD] (col off+d) -> [b*3072+d][2048]
// Grid: 2 * 32 * 48 blocks (b, l-tile, d-tile), 256 threads.
__global__ __launch_bounds__(256)
void tbf16_kernel(const bf16* __restrict__ src, int srcLD, int colOff,
                  bf16* __restrict__ dst) {
  __shared__ unsigned short tile[64][72];  // 72: rows 144B (16B-aligned), low conflict
  int bz = blockIdx.x / (48 * 32);
  int rem = blockIdx.x % (48 * 32);
  int td = rem % 48, tl = rem / 48;
  int l0 = tl * 64, d0 = td * 64;
  const bf16* s0 = src + ((size_t)bz * L_SEQ + l0) * srcLD + colOff + d0;
  // load phase: 512 chunks of 8 bf16 (16B); thread t -> row t>>3, col8 t&7
#pragma unroll
  for (int it = 0; it < 2; ++it) {
    int t = threadIdx.x + it * 256;
    int r = t >> 3, c8 = t & 7;
    bf16x8 v = *(const bf16x8*)(s0 + (size_t)r * srcLD + c8 * 8);
    *(bf16x8*)&tile[r][c8 * 8] = v;
  }
  __syncthreads();
  // store phase: thread t -> d = t&63, l16 = t>>6 (16 l's per thread)
  int dd = threadIdx.x & 63;
  int l16 = threadIdx.x >> 6;
  bf16* dp = dst + ((size_t)bz * DI + d0 + dd) * L_SEQ + l0 + l16 * 16;
  bf16x8 v0, v1;
#pragma unroll
  for (int j = 0; j < 8; ++j) v0[j] = (short)tile[l16 * 16 + j][dd];
#pragma unroll
  for (int j = 0; j < 8; ++j) v1[j] = (short)tile[l16 * 16 + 8 + j][dd];
  *(bf16x8*)dp = v0;
  *(bf16x8*)(dp + 8) = v1;
}

// ---------------- conv: depthwise causal conv(4) + bias + SiLU ---------------
__global__ __launch_bounds__(256)
void conv_kernel(const bf16* __restrict__ xz, const float* __restrict__ conv_w,
                 const float* __restrict__ conv_b, bf16* __restrict__ xconv) {
  int idx = blockIdx.x * 256 + threadIdx.x;  // 0 .. M_TOT*DI-1
  int d = idx % DI;
  int row = idx / DI;
  int l = row & (L_SEQ - 1);
  float4 w4 = *(const float4*)(conv_w + d * 4);
  const float wv[4] = {w4.x, w4.y, w4.z, w4.w};
  float acc = conv_b[d];
#pragma unroll
  for (int t = 0; t < 4; ++t) {
    int ll = l - 3 + t;
    if (ll >= 0) acc += bf2f(xz[(size_t)(row - 3 + t) * 6144 + d]) * wv[t];
  }
  xconv[idx] = f2bf(acc / (1.f + __expf(-acc)));  // silu
}

// ---------------- cast dt_raw slice of x_dbl to bf16 -------------------------
__global__ __launch_bounds__(256)
void dtraw_cast(const float* __restrict__ xdbl, bf16* __restrict__ dtraw) {
  int idx = blockIdx.x * 256 + threadIdx.x;  // 0 .. M_TOT*96-1
  int r = idx / DTR, c = idx - r * DTR;
  dtraw[idx] = f2bf(xdbl[(size_t)r * XDBL_LD + c]);
}

// ---------------- 128x128 bf16 MFMA GEMM (m97 structure) ---------------------
// A: (M, K) bf16 row-major lda; Bt: (N, K) bf16 row-major ldb.
// EPI: 0 = store bf16; 1 = store f32; 2 = softplus(acc + extra[c]) -> bf16;
//      3 = acc + extra[r*ldc+c] -> f32
template <int EPI>
__global__ __launch_bounds__(256)
void gemm128(const bf16* __restrict__ A, int lda, const bf16* __restrict__ Bt,
             int ldb, void* __restrict__ C, int ldc,
             const float* __restrict__ extra, int nTilesN, int K) {
  __shared__ __align__(16) bf16 As[128 * 32];
  __shared__ __align__(16) bf16 Bs[128 * 32];
  const int tid = threadIdx.x;
  const int lane = tid & 63;
  const int wid = tid >> 6;
  const int bm = (blockIdx.x / nTilesN) * 128;
  const int bn = (blockIdx.x % nTilesN) * 128;
  const int wr = wid >> 1, wc = wid & 1;
  f32x4 acc[4][4] = {};
  for (int k0 = 0; k0 < K; k0 += 32) {
#pragma unroll
    for (int it = 0; it < 2; ++it) {
      int chunk = (wid * 2 + it) * 64 + lane;  // 0..511
      int row = chunk >> 2;
      int ke = (chunk & 3) * 8;
      gload_lds16(A + (size_t)(bm + row) * lda + (k0 + ke),
                  (char*)As + (size_t)(wid * 2 + it) * 1024);
      gload_lds16(Bt + (size_t)(bn + row) * ldb + (k0 + ke),
                  (char*)Bs + (size_t)(wid * 2 + it) * 1024);
    }
    __syncthreads();
    bf16x8 af[4], bfr[4];
#pragma unroll
    for (int m = 0; m < 4; ++m)
      af[m] = *(const bf16x8*)(As + (wr * 64 + m * 16 + (lane & 15)) * 32 +
                               (lane >> 4) * 8);
#pragma unroll
    for (int n = 0; n < 4; ++n)
      bfr[n] = *(const bf16x8*)(Bs + (wc * 64 + n * 16 + (lane & 15)) * 32 +
                                (lane >> 4) * 8);
#pragma unroll
    for (int m = 0; m < 4; ++m)
#pragma unroll
      for (int n = 0; n < 4; ++n)
        acc[m][n] =
            __builtin_amdgcn_mfma_f32_16x16x32_bf16(af[m], bfr[n], acc[m][n], 0, 0, 0);
    __syncthreads();
  }
  const int r0 = bm + wr * 64 + (lane >> 4) * 4;
  const int c0 = bn + wc * 64 + (lane & 15);
#pragma unroll
  for (int m = 0; m < 4; ++m) {
#pragma unroll
    for (int n = 0; n < 4; ++n) {
      int c = c0 + n * 16;
#pragma unroll
      for (int j = 0; j < 4; ++j) {
        int r = r0 + m * 16 + j;
        size_t off = (size_t)r * ldc + c;
        float v = acc[m][n][j];
        if constexpr (EPI == 0) {
          ((bf16*)C)[off] = f2bf(v);
        } else if constexpr (EPI == 1) {
          ((float*)C)[off] = v;
        } else if constexpr (EPI == 2) {
          float t = v + extra[c];
          ((bf16*)C)[off] = f2bf(t > 20.f ? t : log1pf(__expf(t)));
        } else {
          ((float*)C)[off] = v + extra[off];
        }
      }
    }
  }
}

// ---------------- chunked selective scan -------------------------------------
// Block: 256 thr = 16 channels x 16 lanes; 6 states/lane.
// Grid: (384, NCHUNK) -> (channel group, chunk).
// PASS 1: recurrence from s=0, emits q (chunk-final state) + sumdt.
// PASS 2: recurrence from corrected start state (in q), emits gated y.
// B (and C for pass 2) staged in double-buffered LDS per 16-step sub-chunk.
template <int PASS>
__global__ __launch_bounds__(256)
void scan_pass(const bf16* __restrict__ dtT, const bf16* __restrict__ xcT,
               const bf16* __restrict__ zT, const float* __restrict__ xdbl,
               const float* __restrict__ A_log, const float* __restrict__ Dp,
               float* __restrict__ q, float* __restrict__ sumdt,
               bf16* __restrict__ yy) {
  constexpr int SW = (PASS == 1) ? 96 : 192;  // staged floats per step
  constexpr int NF4 = SUBS * SW / 4;          // float4s per sub-chunk
  __shared__ float bcs[2][SUBS][SW];
  const int tid = threadIdx.x;
  const int g = tid & 15;
  const int cl = tid >> 4;
  const int ch = blockIdx.x * 16 + cl;  // 0..6143
  const int c = blockIdx.y;             // chunk
  const int b = ch >= DI ? 1 : 0;
  const int d = ch - b * DI;
  const int n0 = g * 6;
  const int l0 = c * CLEN;

  float a2[6];
#pragma unroll
  for (int j = 0; j < 6; ++j)
    a2[j] = -__expf(A_log[(size_t)d * DS + n0 + j]) * LOG2E;

  float s[6];
  if (PASS == 1) {
#pragma unroll
    for (int j = 0; j < 6; ++j) s[j] = 0.f;
  } else {
#pragma unroll
    for (int j = 0; j < 6; ++j)
      s[j] = q[((size_t)ch * NCHUNK + c) * DS + n0 + j];
  }
  const float Dd = (PASS == 2) ? Dp[d] : 0.f;
  float sdt = 0.f;

  const bf16* dtp = dtT + (size_t)ch * L_SEQ + l0;
  const bf16* xcp = xcT + (size_t)ch * L_SEQ + l0;
  const bf16* zp = zT + (size_t)ch * L_SEQ + l0;
  // B (cols 96..191) and C (192..287) are contiguous after col 96
  const float* xb = xdbl + ((size_t)b * L_SEQ + l0) * XDBL_LD + DTR;
  bf16* yp = yy + ((size_t)b * L_SEQ + l0) * DI + d;

  // prologue: stage sub-chunk 0
  float4 rg[3];
#pragma unroll
  for (int k = 0; k < 3; ++k) {
    int f = tid + k * 256;
    if (f < NF4) {
      int row = f / (SW / 4), c4 = f % (SW / 4);
      rg[k] = *(const float4*)(xb + (size_t)row * XDBL_LD + c4 * 4);
    }
  }
#pragma unroll
  for (int k = 0; k < 3; ++k) {
    int f = tid + k * 256;
    if (f < NF4) ((float4*)&bcs[0][0][0])[f] = rg[k];
  }
  __syncthreads();

  int cur = 0;
  for (int sc = 0; sc < NSUB; ++sc) {
    // issue next sub-chunk's global loads early (hide under compute)
    if (sc < NSUB - 1) {
#pragma unroll
      for (int k = 0; k < 3; ++k) {
        int f = tid + k * 256;
        if (f < NF4) {
          int row = f / (SW / 4), c4 = f % (SW / 4);
          rg[k] = *(const float4*)(xb + (size_t)((sc + 1) * SUBS + row) * XDBL_LD +
                                   c4 * 4);
        }
      }
    }
    // per-channel streams for these 16 steps (broadcast within channel group)
    bf16x8 dt8a = *(const bf16x8*)(dtp + sc * SUBS);
    bf16x8 dt8b = *(const bf16x8*)(dtp + sc * SUBS + 8);
    bf16x8 xc8a = *(const bf16x8*)(xcp + sc * SUBS);
    bf16x8 xc8b = *(const bf16x8*)(xcp + sc * SUBS + 8);
    bf16x8 z8a = {}, z8b = {};
    if (PASS == 2) {
      z8a = *(const bf16x8*)(zp + sc * SUBS);
      z8b = *(const bf16x8*)(zp + sc * SUBS + 8);
    }
#pragma unroll
    for (int i = 0; i < SUBS; ++i) {
      float dtv = bfbits(i < 8 ? dt8a[i] : dt8b[i - 8]);
      float xv = bfbits(i < 8 ? xc8a[i] : xc8b[i - 8]);
      float du = dtv * xv;
      if (PASS == 1) sdt += dtv;
      const float* brow = &bcs[cur][i][0];
      float pj = 0.f;
      float2 Bv[3], Cv[3];
#pragma unroll
      for (int j3 = 0; j3 < 3; ++j3) {
        Bv[j3] = *(const float2*)(brow + n0 + 2 * j3);
        if (PASS == 2) Cv[j3] = *(const float2*)(brow + 96 + n0 + 2 * j3);
      }
#pragma unroll
      for (int j = 0; j < 6; ++j) {
        float e = fexp2(dtv * a2[j]);
        float Bj = (j & 1) ? Bv[j >> 1].y : Bv[j >> 1].x;
        s[j] = s[j] * e + du * Bj;
        if (PASS == 2) {
          float Cj = (j & 1) ? Cv[j >> 1].y : Cv[j >> 1].x;
          pj += s[j] * Cj;
        }
      }
      if (PASS == 2) {
        pj += __shfl_xor(pj, 8);
        pj += __shfl_xor(pj, 4);
        pj += __shfl_xor(pj, 2);
        pj += __shfl_xor(pj, 1);
        if (g == 0) {
          float zv = bfbits(i < 8 ? z8a[i] : z8b[i - 8]);
          float y = pj + xv * Dd;
          yp[(size_t)(sc * SUBS + i) * DI] = f2bf(y * (zv / (1.f + __expf(-zv))));
        }
      }
    }
    if (sc < NSUB - 1) {
#pragma unroll
      for (int k = 0; k < 3; ++k) {
        int f = tid + k * 256;
        if (f < NF4) ((float4*)&bcs[cur ^ 1][0][0])[f] = rg[k];
      }
      __syncthreads();
      cur ^= 1;
    }
  }

  if (PASS == 1) {
    float* qp = q + ((size_t)ch * NCHUNK + c) * DS + n0;
#pragma unroll
    for (int j = 0; j < 6; ++j) qp[j] = s[j];
    if (g == 0) sumdt[ch * NCHUNK + c] = sdt;
  }
}

// ---------------- combine: sequential chunk fix-up (in-place on q) -----------
// q[ch][c][:] on entry: chunk-final state from s=0. On exit: chunk START state.
__global__ __launch_bounds__(256)
void scan_combine(const float* __restrict__ A_log, float* __restrict__ q,
                  const float* __restrict__ sumdt) {
  int idx = blockIdx.x * 256 + threadIdx.x;  // 0..98303
  int ch = idx >> 4, g = idx & 15;
  int b = ch >= DI ? 1 : 0;
  int d = ch - b * DI;
  int n0 = g * 6;
  float a2[6];
#pragma unroll
  for (int j = 0; j < 6; ++j)
    a2[j] = -__expf(A_log[(size_t)d * DS + n0 + j]) * LOG2E;
  float s[6] = {0.f, 0.f, 0.f, 0.f, 0.f, 0.f};
  for (int c = 0; c < NCHUNK; ++c) {
    float sd = sumdt[ch * NCHUNK + c];
    float* qp = q + ((size_t)ch * NCHUNK + c) * DS + n0;
    float qc[6];
#pragma unroll
    for (int j = 0; j < 6; ++j) {
      qc[j] = qp[j];
      qp[j] = s[j];  // start state for chunk c
    }
#pragma unroll
    for (int j = 0; j < 6; ++j) {
      float P = fexp2(a2[j] * sd);
      s[j] = P * s[j] + qc[j];
    }
  }
}

// ---------------- launch ------------------------------------------------------
extern "C" void kernel_launch(void* const* d_in, const int* in_sizes, int n_in,
                              void* d_out, int out_size, void* d_ws,
                              size_t ws_size, hipStream_t stream) {
  const float* x = (const float*)d_in[0];
  const float* t_cond = (const float*)d_in[1];
  const float* cond_w = (const float*)d_in[2];
  const float* cond_b = (const float*)d_in[3];
  const float* in_w = (const float*)d_in[4];
  const float* conv_w = (const float*)d_in[5];
  const float* conv_b = (const float*)d_in[6];
  const float* xproj_w = (const float*)d_in[7];
  const float* dt_w = (const float*)d_in[8];
  const float* dt_b = (const float*)d_in[9];
  const float* A_log = (const float*)d_in[10];
  const float* D_p = (const float*)d_in[11];
  const float* out_w = (const float*)d_in[12];
  float* out = (float*)d_out;

  char* ws = (char*)d_ws;
  size_t off = 0;
  auto alloc = [&](size_t bytes) {
    void* p = ws + off;
    off += (bytes + 255) & ~(size_t)255;
    return p;
  };
  // ~151.1 MB total
  float* cond_mod = (float*)alloc(2 * 4608 * 4);
  // regionA: xm (12.58MB) + in_w_t (18.87MB), both dead after G1 -> xcT
  char* regionA = (char*)alloc(31457280);
  bf16* xm = (bf16*)regionA;
  bf16* in_w_t = (bf16*)(regionA + (size_t)M_TOT * DM * 2);
  bf16* xcT = (bf16*)regionA;  // [2*3072][2048] bf16, written step 10
  bf16* xproj_t = (bf16*)alloc((size_t)XDBL_LD * DI * 2);
  bf16* dtw_t = (bf16*)alloc((size_t)DI * DTR * 2);
  bf16* outw_t = (bf16*)alloc((size_t)DM * DI * 2);
  // xz region (50.33MB): dead after zT (step 11) -> dtT + dtraw + yy
  char* xzR = (char*)alloc((size_t)M_TOT * 6144 * 2);
  bf16* xz = (bf16*)xzR;
  bf16* dtT = (bf16*)xzR;                          // 25.17MB
  bf16* dtraw = (bf16*)(xzR + 25165824);           // 0.79MB
  bf16* yy = (bf16*)(xzR + 25952256);              // 12.58MB
  // xconv region (25.17MB): dead after xcT (step 10) -> zT (step 11)
  char* xcR = (char*)alloc((size_t)M_TOT * DI * 2);
  bf16* xconv = (bf16*)xcR;
  bf16* zT = (bf16*)xcR;
  float* xdbl = (float*)alloc((size_t)M_TOT * XDBL_LD * 4);
  // dtbuf (25.17MB): dead after dtT transpose (step 14) -> q (18.87MB)
  char* dtR = (char*)alloc((size_t)M_TOT * DI * 2);
  bf16* dtbuf = (bf16*)dtR;
  float* qbuf = (float*)dtR;
  float* sumdt = (float*)alloc((size_t)2 * DI * NCHUNK * 4);  // 196KB

  // 1. conditioning
  cond_kernel<<<36, 256, 0, stream>>>(t_cond, cond_w, cond_b, cond_mod);
  // 2. rmsnorm + modulation
  rmsmod_kernel<<<M_TOT, 256, 0, stream>>>(x, cond_mod, xm);
  // 3-6. weight transpose-casts
  transpose_cast<<<dim3(96, 24), 256, 0, stream>>>(in_w, in_w_t, 1536, 6144, 6144);
  transpose_cast<<<dim3(6, 48), 256, 0, stream>>>(xproj_w, xproj_t, 3072, 288, 384);
  transpose_cast<<<dim3(48, 2), 256, 0, stream>>>(dt_w, dtw_t, 96, 3072, 3072);
  transpose_cast<<<dim3(24, 48), 256, 0, stream>>>(out_w, outw_t, 3072, 1536, 1536);
  // 7. G1: xz = xm @ in_w  (4096 x 6144 x 1536) -> bf16
  gemm128<0><<<32 * 48, 256, 0, stream>>>(xm, DM, in_w_t, DM, xz, 6144,
                                          nullptr, 48, DM);
  // 8. conv + silu
  conv_kernel<<<(M_TOT * DI) / 256, 256, 0, stream>>>(xz, conv_w, conv_b, xconv);
  // 9. G2: x_dbl = xconv @ xproj (4096 x 384pad x 3072) -> f32
  gemm128<1><<<32 * 3, 256, 0, stream>>>(xconv, DI, xproj_t, DI, xdbl, XDBL_LD,
                                         nullptr, 3, DI);
  // 10. xcT = transpose(xconv)   (frees xconv region)
  tbf16_kernel<<<2 * 48 * 32, 256, 0, stream>>>(xconv, DI, 0, xcT);
  // 11. zT = transpose(z half of xz)   (frees xz region)
  tbf16_kernel<<<2 * 48 * 32, 256, 0, stream>>>(xz, 6144, DI, zT);
  // 12. dt_raw cast (into freed xz region)
  dtraw_cast<<<(M_TOT * DTR) / 256, 256, 0, stream>>>(xdbl, dtraw);
  // 13. G3: dt = softplus(dt_raw @ dt_w + dt_b) (4096 x 3072 x 96) -> bf16
  gemm128<2><<<32 * 24, 256, 0, stream>>>(dtraw, DTR, dtw_t, DTR, dtbuf, DI,
                                          dt_b, 24, DTR);
  // 14. dtT = transpose(dt)   (frees dtbuf region -> q)
  tbf16_kernel<<<2 * 48 * 32, 256, 0, stream>>>(dtbuf, DI, 0, dtT);
  // 15a. chunk summaries
  scan_pass<1><<<dim3(384, NCHUNK), 256, 0, stream>>>(
      dtT, xcT, zT, xdbl, A_log, D_p, qbuf, sumdt, yy);
  // 15b. sequential chunk combine (q becomes start states)
  scan_combine<<<384, 256, 0, stream>>>(A_log, qbuf, sumdt);
  // 15c. chunked scan with outputs + gated epilogue -> yy
  scan_pass<2><<<dim3(384, NCHUNK), 256, 0, stream>>>(
      dtT, xcT, zT, xdbl, A_log, D_p, qbuf, sumdt, yy);
  // 16. G4: out = x + yy @ out_w (4096 x 1536 x 3072) -> f32
  gemm128<3><<<32 * 12, 256, 0, stream>>>(yy, DI, outw_t, DI, out, DM, x, 12,
                                          DI);
}